// Round 11
// baseline (153.302 us; speedup 1.0000x reference)
//
#include <hip/hip_runtime.h>
#include <float.h>

typedef __attribute__((ext_vector_type(8))) short short8;
typedef __attribute__((ext_vector_type(4))) float f32x4;

#define BT    16384      // B*T tokens
#define DM    256        // embedding dim
#define KC    8192       // codebook size
#define QOFF  (BT * DM)  // start of indices in d_out
#define LOFF  (QOFF + BT)
#define MARGIN 2e-4f

// ws layout (bytes)
#define E_XH 0
#define E_CH (BT * DM)                                   // ushort elems
#define WS_BF16_BYTES ((size_t)(BT * DM + KC * DM) * 2)  // 12582912
#define WS_SLOT_OFF   WS_BF16_BYTES                      // uint2[64][BT] = 8 MB
#define WS_SLOT_BYTES ((size_t)64 * BT * 8)
#define WS_LP_OFF     (WS_SLOT_OFF + WS_SLOT_BYTES)
#define WS_NEED       (WS_LP_OFF + 4096 * 4)

// ======================= MFMA path =======================

__device__ inline ushort bf16rne(float f) {
    unsigned u = __float_as_uint(f);
    return (ushort)((u + 0x7FFFu + ((u >> 16) & 1u)) >> 16);
}
__device__ inline unsigned umax2(unsigned a, unsigned b) { return a > b ? a : b; }
__device__ inline unsigned umin2(unsigned a, unsigned b) { return a < b ? a : b; }

// async global->LDS, 16B per lane; dest = lds base (wave-uniform) + lane*16
__device__ __forceinline__ void gl_lds16(const void* g, void* l) {
    __builtin_amdgcn_global_load_lds(
        (const __attribute__((address_space(1))) void*)g,
        (__attribute__((address_space(3))) void*)l, 16, 0, 0);
}

// k_cvt: one-time bf16 round of x and codebook into ws
__global__ __launch_bounds__(256) void k_cvt(const float* __restrict__ x,
                                             const float* __restrict__ cb,
                                             ushort* __restrict__ ws) {
    const int XN = BT * DM / 4;
    const int CN = KC * DM / 4;
    int idx = blockIdx.x * 256 + threadIdx.x;
    const float4* src;
    ushort* dh; int o;
    if (idx < XN) { src = (const float4*)x; dh = ws + E_XH; o = idx; }
    else {
        o = idx - XN;
        if (o >= CN) return;
        src = (const float4*)cb; dh = ws + E_CH;
    }
    float4 v = src[o];
    ushort4 h;
    h.x = bf16rne(v.x);
    h.y = bf16rne(v.y);
    h.z = bf16rne(v.z);
    h.w = bf16rne(v.w);
    ((ushort4*)dh)[o] = h;
}

// k_main_mfma v9: token-stationary, 1 wave/block, ZERO barriers.
// grid 2048 = 256 token-tiles x 8 splits (split = bid&7 = XCD -> its 512KB
// code slice stays L2-resident; bf16 codebook is 4MB total).
// Wave holds B = 64 tokens full-D in regs (b[4][8], 128 VGPR); A = codes
// stream through a wave-PRIVATE 2x8KB LDS dbuf via global_load_lds with
// pre-swizzled source (R9-verified layout). Per 16-code panel: 8 ds_read +
// 32 MFMA + lane-local packed-key top-2 insert (C col = lane&15 = token is
// FIXED -> no cross-lane work until group end). Every 8 panels (=128-code
// group): lq-butterfly + uint2 slot store (same format as R10, verified).
// DMA discipline: issue next panel, compute current, s_waitcnt vmcnt(0) +
// sched_barrier(0) (rule #18), swap. No __syncthreads anywhere.
__global__ __launch_bounds__(64, 2) void k_main_mfma(const ushort* __restrict__ ws,
                                                     uint2* __restrict__ slotb) {
    __shared__ ushort sCod[2][16 * 256];   // 2 x 8 KB wave-private code panels

    const int L  = threadIdx.x;            // 0..63
    const int lq = L >> 4, lr = L & 15;
    const int split = blockIdx.x & 7;
    const int tt    = blockIdx.x >> 3;
    const int t0    = tt * 64;
    const int c0    = split * 1024;
    const unsigned idlq = (unsigned)lq << 2;

    const short8* xh8 = (const short8*)(ws + E_XH);
    const uint4*  ch4 = (const uint4*)(ws + E_CH);

    // B (tokens) register-resident: b[j][ks] = token t0+j*16+lr, k-granule ks*4+lq
    short8 b[4][8];
    #pragma unroll
    for (int j = 0; j < 4; ++j)
        #pragma unroll
        for (int ks = 0; ks < 8; ++ks)
            b[j][ks] = xh8[(size_t)(t0 + j * 16 + lr) * 32 + ks * 4 + lq];

    const int half = L >> 5;     // row parity within a 2-row DMA
    const int g32  = L & 31;     // linear dest granule

    // prologue: DMA panel 0 into buf 0 (16 code rows x 512B, pre-swizzled src)
    {
        const uint4* src = ch4 + (size_t)c0 * 32;
        #pragma unroll
        for (int q = 0; q < 8; ++q) {
            int rrel = 2 * q + half;
            gl_lds16(src + (size_t)rrel * 32 + (g32 ^ (rrel & 7)),
                     &sCod[0][q * 512]);
        }
    }
    asm volatile("s_waitcnt vmcnt(0)" ::: "memory");
    __builtin_amdgcn_sched_barrier(0);

    for (int g = 0; g < 8; ++g) {
        unsigned Hk[4], Lk[4];
        #pragma unroll
        for (int j = 0; j < 4; ++j) { Hk[j] = 0u; Lk[j] = 0u; }

        #pragma unroll
        for (int p = 0; p < 8; ++p) {
            const int panel = g * 8 + p;
            const int buf   = panel & 1;

            // DMA next panel into the dead buffer (lands during compute)
            if (panel < 63) {
                const uint4* src = ch4 + (size_t)(c0 + (panel + 1) * 16) * 32;
                #pragma unroll
                for (int q = 0; q < 8; ++q) {
                    int rrel = 2 * q + half;
                    gl_lds16(src + (size_t)rrel * 32 + (g32 ^ (rrel & 7)),
                             &sCod[buf ^ 1][q * 512]);
                }
            }

            // compute panel: 8 K=32 steps, A (16 codes) from LDS x B regs
            f32x4 acc[4];
            #pragma unroll
            for (int j = 0; j < 4; ++j)
                acc[j] = (f32x4){0.25f, 0.25f, 0.25f, 0.25f};   // positive bias

            const ushort* cbuf = &sCod[buf][0];
            #pragma unroll
            for (int ks = 0; ks < 8; ++ks) {
                short8 a = *(const short8*)(cbuf + lr * 256 + (((ks * 4 + lq) ^ (lr & 7)) * 8));
                #pragma unroll
                for (int j = 0; j < 4; ++j)
                    acc[j] = __builtin_amdgcn_mfma_f32_16x16x32_bf16(a, b[j][ks], acc[j], 0, 0, 0);
            }

            // lane-local packed-key top-2 insert (code id = p*16 + lq*4 + r)
            const unsigned idb = ((unsigned)p << 4) | idlq;
            #pragma unroll
            for (int j = 0; j < 4; ++j) {
                unsigned e0 = (__float_as_uint(acc[j][0]) & 0xFFFFFF80u) | idb;
                unsigned e1 = (__float_as_uint(acc[j][1]) & 0xFFFFFF80u) | idb | 1u;
                unsigned e2 = (__float_as_uint(acc[j][2]) & 0xFFFFFF80u) | idb | 2u;
                unsigned e3 = (__float_as_uint(acc[j][3]) & 0xFFFFFF80u) | idb | 3u;
                unsigned h1 = umax2(e0, e1), l1 = umin2(e0, e1);
                unsigned h2 = umax2(e2, e3), l2 = umin2(e2, e3);
                unsigned hh = umax2(h1, h2);
                unsigned hl = umax2(umin2(h1, h2), umax2(l1, l2));
                unsigned nH = umax2(Hk[j], hh);
                Lk[j] = umax2(umin2(Hk[j], hh), umax2(Lk[j], hl));
                Hk[j] = nH;
            }

            // drain the in-flight DMA before swapping buffers next iteration
            asm volatile("s_waitcnt vmcnt(0)" ::: "memory");
            __builtin_amdgcn_sched_barrier(0);
        }

        // group finalize: butterfly over lq (lanes xor 16, 32), store, reset
        #pragma unroll
        for (int j = 0; j < 4; ++j) {
            unsigned H = Hk[j], Lo = Lk[j];
            #pragma unroll
            for (int off = 16; off <= 32; off <<= 1) {
                unsigned oH = (unsigned)__shfl_xor((int)H, off);
                unsigned oL = (unsigned)__shfl_xor((int)Lo, off);
                unsigned m = umin2(H, oH);
                H  = umax2(H, oH);
                Lo = umax2(m, umax2(Lo, oL));
            }
            if (L < 16)
                slotb[(size_t)(split * 8 + g) * BT + t0 + j * 16 + lr] = make_uint2(H, Lo);
        }
    }
}

// k_gather: fused candidate-collect + exact np-f32 re-check + gather + loss.
// One wave per token; slot L (= grp L) read as raw uint2 packed keys.
__global__ __launch_bounds__(256) void k_gather(const float* __restrict__ x,
                                                const float* __restrict__ cb,
                                                const uint2* __restrict__ slotb,
                                                float* __restrict__ out,
                                                float* __restrict__ lp) {
    __shared__ float4 xls[4][64];
    __shared__ int candk[4][16];
    __shared__ float bsum[4];

    const int w = threadIdx.x >> 6;
    const int L = threadIdx.x & 63;
    const int t = blockIdx.x * 4 + w;

    const float4 xv = ((const float4*)x)[(size_t)t * 64 + L];
    xls[w][L] = xv;

    const uint2 s = slotb[(size_t)L * BT + t];
    float v1 = __uint_as_float(s.x & 0xFFFFFF80u);   // biased (+0.25), monotone
    float v2 = __uint_as_float(s.y & 0xFFFFFF80u);
    int   k1 = L * 128 + (int)(s.x & 127u);
    int   k2 = L * 128 + (int)(s.y & 127u);

    // global argmax (min-k tie)
    float lm = v1; int lk = k1;
    #pragma unroll
    for (int off = 32; off; off >>= 1) {
        float ov = __shfl_xor(lm, off);
        int   ok = __shfl_xor(lk, off);
        if (ov > lm || (ov == lm && ok < lk)) { lm = ov; lk = ok; }
    }
    const float thr = lm - MARGIN;

    int* ct = candk[w];
    if (L == 0) ct[0] = lk;          // argmax always candidate 0
    int ncand = 1;
    #pragma unroll
    for (int ph = 0; ph < 2; ++ph) {
        float vv = ph ? v2 : v1;
        int   kf = ph ? k2 : k1;
        unsigned long long bal = __ballot(vv >= thr);
        while (bal) {
            int src = __ffsll(bal) - 1;
            bal &= bal - 1;
            int kv = __shfl(kf, src);
            if (L == 0 && ncand < 16) ct[ncand] = kv;
            ncand++;
        }
    }
    if (ncand > 16) ncand = 16;

    int best;
    if (ncand <= 1) {
        best = lk;
    } else {
        // x2 (any f32 within ~1e-4 of numpy's: uniform grid shift)
        double dl = (double)xv.x * xv.x + (double)xv.y * xv.y
                  + (double)xv.z * xv.z + (double)xv.w * xv.w;
        #pragma unroll
        for (int off = 32; off; off >>= 1) dl += __shfl_xor(dl, off);
        const float x2 = (float)dl;

        const int g = L >> 2, l4 = L & 3;
        float sex = FLT_MAX;
        int   kk  = 0x7fffffff;
        if (g < ncand) {
            kk = ct[g];
            const float* xr = (const float*)&xls[w][0];
            const float* cr = cb + (size_t)kk * DM;
            float acc = 0.f;
            {
#pragma clang fp contract(off)
                #pragma unroll 8
                for (int m = 0; m < 64; m++) {
                    float p2 = xr[4 * m + l4] * cr[4 * m + l4];
                    acc = acc + p2;
                }
            }
            float t1 = acc + __shfl_xor(acc, 1);   // fl(s0+s1)/fl(s2+s3)
            float xc = t1 + __shfl_xor(t1, 2);     // np 4-acc SSE combine
            sex = x2 - 2.0f * xc;
        }
        #pragma unroll
        for (int off = 32; off; off >>= 1) {
            float os = __shfl_xor(sex, off);
            int   ok = __shfl_xor(kk, off);
            if (os < sex || (os == sex && ok < kk)) { sex = os; kk = ok; }
        }
        best = kk;
    }

    const float4 cv = ((const float4*)cb)[(size_t)best * 64 + L];
    float4 e, q;
    e.x = cv.x - xv.x; q.x = xv.x + e.x;
    e.y = cv.y - xv.y; q.y = xv.y + e.y;
    e.z = cv.z - xv.z; q.z = xv.z + e.z;
    e.w = cv.w - xv.w; q.w = xv.w + e.w;
    ((float4*)out)[(size_t)t * 64 + L] = q;
    if (L == 0) out[QOFF + t] = (float)best;

    float ls = e.x * e.x + e.y * e.y + e.z * e.z + e.w * e.w;
    #pragma unroll
    for (int off = 32; off; off >>= 1) ls += __shfl_xor(ls, off);
    if (L == 0) bsum[w] = ls;
    __syncthreads();
    if (threadIdx.x == 0)
        lp[blockIdx.x] = bsum[0] + bsum[1] + bsum[2] + bsum[3];
}

// ======================= fallback f32 path (round-2, verified) =======================

#define TM    64
#define TK    64
#define NSPLIT 2
#define KPS   (KC / NSPLIT)
#define LDSW  68

__global__ __launch_bounds__(256, 2) void k_main_f32(const float* __restrict__ x,
                                                     const float* __restrict__ cb,
                                                     float* __restrict__ out) {
    __shared__ float xs[TM * LDSW];
    __shared__ float cs[TK * LDSW];

    const int tid = threadIdx.x;
    const int ty = tid >> 4, tx = tid & 15;
    const int split = blockIdx.x & 1;
    const int tb    = blockIdx.x >> 1;
    const int t0    = tb * TM;
    const int kb0   = split * KPS;
    const int txc   = tx & 7;
    const int srow = tid >> 4;
    const int sc4  = tid & 15;
    const float4* x4  = (const float4*)x;
    const float4* cb4 = (const float4*)cb;

    float mv[4][4];
    int   mi[4][4];
    #pragma unroll
    for (int i = 0; i < 4; i++)
        #pragma unroll
        for (int j = 0; j < 4; j++) { mv[i][j] = -FLT_MAX; mi[i][j] = 0; }

    for (int k0 = 0; k0 < KPS; k0 += TK) {
        float dot[4][4];
        #pragma unroll
        for (int i = 0; i < 4; i++)
            #pragma unroll
            for (int j = 0; j < 4; j++) dot[i][j] = 0.f;

        for (int d0 = 0; d0 < DM; d0 += 64) {
            __syncthreads();
            const int d04 = d0 >> 2;
            #pragma unroll
            for (int r = 0; r < 4; r++) {
                int row = srow + 16 * r;
                float4 xv = x4[(size_t)(t0 + row) * 64 + d04 + sc4];
                *(float4*)&xs[row * LDSW + sc4 * 4] = xv;
                int gc = sc4 ^ ((row >> 2) & 7);
                float4 cv = cb4[(size_t)(kb0 + k0 + row) * 64 + d04 + gc];
                *(float4*)&cs[row * LDSW + sc4 * 4] = cv;
            }
            __syncthreads();

            #pragma unroll
            for (int u = 0; u < 16; u++) {
                float4 xa[4];
                #pragma unroll
                for (int i = 0; i < 4; i++)
                    xa[i] = *(const float4*)&xs[(ty * 4 + i) * LDSW + u * 4];
                const int ww = u ^ txc;
                float4 cv[4];
                #pragma unroll
                for (int j = 0; j < 4; j++)
                    cv[j] = *(const float4*)&cs[(tx * 4 + j) * LDSW + ww * 4];
                #pragma unroll
                for (int i = 0; i < 4; i++)
                    #pragma unroll
                    for (int j = 0; j < 4; j++) {
                        dot[i][j] = fmaf(xa[i].x, cv[j].x, dot[i][j]);
                        dot[i][j] = fmaf(xa[i].y, cv[j].y, dot[i][j]);
                        dot[i][j] = fmaf(xa[i].z, cv[j].z, dot[i][j]);
                        dot[i][j] = fmaf(xa[i].w, cv[j].w, dot[i][j]);
                    }
            }
        }

        const int kk0 = kb0 + k0 + tx * 4;
        #pragma unroll
        for (int i = 0; i < 4; i++)
            #pragma unroll
            for (int j = 0; j < 4; j++) {
                float d = dot[i][j];
                int   kk = kk0 + j;
                if (d > mv[i][3]) {
                    if (d > mv[i][1]) {
                        if (d > mv[i][0]) {
                            mv[i][3]=mv[i][2]; mi[i][3]=mi[i][2];
                            mv[i][2]=mv[i][1]; mi[i][2]=mi[i][1];
                            mv[i][1]=mv[i][0]; mi[i][1]=mi[i][0];
                            mv[i][0]=d;        mi[i][0]=kk;
                        } else {
                            mv[i][3]=mv[i][2]; mi[i][3]=mi[i][2];
                            mv[i][2]=mv[i][1]; mi[i][2]=mi[i][1];
                            mv[i][1]=d;        mi[i][1]=kk;
                        }
                    } else {
                        if (d > mv[i][2]) {
                            mv[i][3]=mv[i][2]; mi[i][3]=mi[i][2];
                            mv[i][2]=d;        mi[i][2]=kk;
                        } else {
                            mv[i][3]=d;        mi[i][3]=kk;
                        }
                    }
                }
            }
    }

    #pragma unroll
    for (int i = 0; i < 4; i++) {
        int t = t0 + ty * 4 + i;
        float4 v4 = { mv[i][0], mv[i][1], mv[i][2], mv[i][3] };
        float4 k4 = { (float)mi[i][0], (float)mi[i][1], (float)mi[i][2], (float)mi[i][3] };
        float4* dst = (float4*)(out + (size_t)t * DM + (split * 16 + tx) * 8);
        dst[0] = v4;
        dst[1] = k4;
    }
}

__global__ __launch_bounds__(256) void k_gather_f32(const float* __restrict__ x,
                                                    const float* __restrict__ cb,
                                                    float* __restrict__ out,
                                                    float* __restrict__ lp) {
    __shared__ float4 xls[4][64];
    __shared__ int candk[4][20];
    __shared__ float bsum[4];

    const int w = threadIdx.x >> 6;
    const int L = threadIdx.x & 63;
    const int t = blockIdx.x * 4 + w;

    const float4 xv = ((const float4*)x)[(size_t)t * 64 + L];
    xls[w][L] = xv;
    const float4 f = ((const float4*)(out + (size_t)t * DM))[L];
    const bool even = ((L & 1) == 0);

    double dl = (double)xv.x * xv.x + (double)xv.y * xv.y
              + (double)xv.z * xv.z + (double)xv.w * xv.w;
    #pragma unroll
    for (int off = 32; off; off >>= 1) dl += __shfl_xor(dl, off);
    const float x2 = (float)dl;

    float lm = even ? fmaxf(fmaxf(f.x, f.y), fmaxf(f.z, f.w)) : -FLT_MAX;
    #pragma unroll
    for (int off = 32; off; off >>= 1) lm = fmaxf(lm, __shfl_xor(lm, off));
    const float thr = lm - 5e-5f;

    int ncand = 0;
    #pragma unroll
    for (int j = 0; j < 4; j++) {
        float vj = (j == 0) ? f.x : (j == 1) ? f.y : (j == 2) ? f.z : f.w;
        bool flag = even && (vj >= thr);
        unsigned long long bal = __ballot(flag);
        while (bal) {
            int src = __ffsll(bal) - 1;
            bal &= bal - 1;
            float kv = __shfl(vj, src + 1);
            if (L == 0 && ncand < 20) candk[w][ncand] = (int)kv;
            ncand++;
        }
    }
    if (ncand > 16) ncand = 16;

    int best;
    if (ncand == 1) {
        best = candk[w][0];
    } else {
        const int g = L >> 2, l4 = L & 3;
        float sex = FLT_MAX;
        int   kk  = 0x7fffffff;
        if (g < ncand) {
            kk = candk[w][g];
            const float* xr = (const float*)&xls[w][0];
            const float* cr = cb + (size_t)kk * DM;
            float acc = 0.f;
            {
#pragma clang fp contract(off)
                #pragma unroll 8
                for (int m = 0; m < 64; m++) {
                    float p = xr[4 * m + l4] * cr[4 * m + l4];
                    acc = acc + p;
                }
            }
            float t1 = acc + __shfl_xor(acc, 1);
            float xc = t1 + __shfl_xor(t1, 2);
            sex = x2 - 2.0f * xc;
        }
        #pragma unroll
        for (int off = 32; off; off >>= 1) {
            float os = __shfl_xor(sex, off);
            int   ok = __shfl_xor(kk, off);
            if (os < sex || (os == sex && ok < kk)) { sex = os; kk = ok; }
        }
        best = kk;
    }

    const float4 cv = ((const float4*)cb)[(size_t)best * 64 + L];
    float4 e, q;
    e.x = cv.x - xv.x; q.x = xv.x + e.x;
    e.y = cv.y - xv.y; q.y = xv.y + e.y;
    e.z = cv.z - xv.z; q.z = xv.z + e.z;
    e.w = cv.w - xv.w; q.w = xv.w + e.w;
    ((float4*)out)[(size_t)t * 64 + L] = q;
    if (L == 0) out[QOFF + t] = (float)best;

    float ls = e.x * e.x + e.y * e.y + e.z * e.z + e.w * e.w;
    #pragma unroll
    for (int off = 32; off; off >>= 1) ls += __shfl_xor(ls, off);
    if (L == 0) bsum[w] = ls;
    __syncthreads();
    if (threadIdx.x == 0)
        lp[blockIdx.x] = bsum[0] + bsum[1] + bsum[2] + bsum[3];
}

// ---------------- shared loss finalize ----------------
__global__ __launch_bounds__(256) void k_loss(const float* __restrict__ lp,
                                              float* __restrict__ out) {
    __shared__ double sd[256];
    double s = 0.0;
    for (int i = threadIdx.x; i < BT / 4; i += 256) s += (double)lp[i];
    sd[threadIdx.x] = s;
    __syncthreads();
    for (int st = 128; st; st >>= 1) {
        if (threadIdx.x < st) sd[threadIdx.x] += sd[threadIdx.x + st];
        __syncthreads();
    }
    if (threadIdx.x == 0)
        out[LOFF] = (float)(2.0 * sd[0] / (double)QOFF);
}

extern "C" void kernel_launch(void* const* d_in, const int* in_sizes, int n_in,
                              void* d_out, int out_size, void* d_ws, size_t ws_size,
                              hipStream_t stream) {
    const float* x  = (const float*)d_in[0];
    const float* cb = (const float*)d_in[1];
    float* out = (float*)d_out;

    if (ws_size >= (size_t)WS_NEED) {
        ushort* wsu   = (ushort*)d_ws;
        uint2*  slotb = (uint2*)((char*)d_ws + WS_SLOT_OFF);
        float*  lp    = (float*)((char*)d_ws + WS_LP_OFF);
        k_cvt      <<<6144, 256, 0, stream>>>(x, cb, wsu);
        k_main_mfma<<<2048, 64,  0, stream>>>(wsu, slotb);
        k_gather   <<<BT / 4, 256, 0, stream>>>(x, cb, slotb, out, lp);
        k_loss     <<<1,    256, 0, stream>>>(lp, out);
    } else {
        float* lp = (float*)d_ws;
        k_main_f32  <<<(BT / TM) * NSPLIT, 256, 0, stream>>>(x, cb, out);
        k_gather_f32<<<BT / 4,             256, 0, stream>>>(x, cb, out, lp);
        k_loss      <<<1,                  256, 0, stream>>>(lp, out);
    }
}

// Round 12
// 107.380 us; speedup vs baseline: 1.4277x; 1.4277x over previous
//
#include <hip/hip_runtime.h>
#include <float.h>

typedef __attribute__((ext_vector_type(8))) short short8;
typedef __attribute__((ext_vector_type(4))) float f32x4;

#define BT    16384      // B*T tokens
#define DM    256        // embedding dim
#define KC    8192       // codebook size
#define QOFF  (BT * DM)  // start of indices in d_out
#define LOFF  (QOFF + BT)
#define MARGIN 2e-4f

// ws layout (bytes)
#define E_XH 0
#define E_CH (BT * DM)                                   // ushort elems
#define WS_BF16_BYTES ((size_t)(BT * DM + KC * DM) * 2)  // 12582912
#define WS_SLOT_OFF   WS_BF16_BYTES                      // uint2[64][BT] = 8 MB
#define WS_SLOT_BYTES ((size_t)64 * BT * 8)
#define WS_LP_OFF     (WS_SLOT_OFF + WS_SLOT_BYTES)
#define WS_NEED       (WS_LP_OFF + 4096 * 4)

// ======================= MFMA path =======================

__device__ inline ushort bf16rne(float f) {
    unsigned u = __float_as_uint(f);
    return (ushort)((u + 0x7FFFu + ((u >> 16) & 1u)) >> 16);
}
__device__ inline unsigned umax2(unsigned a, unsigned b) { return a > b ? a : b; }
__device__ inline unsigned umin2(unsigned a, unsigned b) { return a < b ? a : b; }

// async global->LDS, 16B per lane; dest = lds base (wave-uniform) + lane*16
__device__ __forceinline__ void gl_lds16(const void* g, void* l) {
    __builtin_amdgcn_global_load_lds(
        (const __attribute__((address_space(1))) void*)g,
        (__attribute__((address_space(3))) void*)l, 16, 0, 0);
}

// k_cvt: one-time bf16 round of x and codebook into ws
__global__ __launch_bounds__(256) void k_cvt(const float* __restrict__ x,
                                             const float* __restrict__ cb,
                                             ushort* __restrict__ ws) {
    const int XN = BT * DM / 4;
    const int CN = KC * DM / 4;
    int idx = blockIdx.x * 256 + threadIdx.x;
    const float4* src;
    ushort* dh; int o;
    if (idx < XN) { src = (const float4*)x; dh = ws + E_XH; o = idx; }
    else {
        o = idx - XN;
        if (o >= CN) return;
        src = (const float4*)cb; dh = ws + E_CH;
    }
    float4 v = src[o];
    ushort4 h;
    h.x = bf16rne(v.x);
    h.y = bf16rne(v.y);
    h.z = bf16rne(v.z);
    h.w = bf16rne(v.w);
    ((ushort4*)dh)[o] = h;
}

// k_main_mfma (R9-verified structure, 81.5us): code-stationary, 4 waves,
// grid 512 = 64 grps x 8 chunks (chunk = bid&7 = XCD -> tokens L2-resident).
// Wave: 64 codes reg-resident full-D (a[4][8], 128 VGPR) x 32 tokens.
// Token panels (64 x 256 = 32 KB) double-buffered via global_load_lds with
// PRE-SWIZZLED source + linear LDS dest. Packed-key top-2 fold + pipelined
// pair-merge. ONLY delta vs R9: merge stores raw uint2 packed keys to the
// ws slot buffer (no float decode, half the slot bytes).
__global__ __launch_bounds__(256, 2) void k_main_mfma(const ushort* __restrict__ ws,
                                                      uint2* __restrict__ slotb) {
    __shared__ ushort sTok[2][64 * 256];   // 2 x 32 KB token panels
    __shared__ uint2  msc[2][2][64];       // [buf][wm][token-local], 2 KB

    const int tid = threadIdx.x;
    const int w = tid >> 6, L = tid & 63;
    const int lq = L >> 4, lr = L & 15;
    const int wm = w >> 1, wn = w & 1;
    const int grp   = blockIdx.x >> 3;
    const int chunk = blockIdx.x & 7;
    const int c0    = grp * 128 + wm * 64;
    const int tok0  = chunk * 2048;
    const unsigned lw = ((unsigned)wm << 6) | ((unsigned)lq << 2);

    const short8* ch8 = (const short8*)(ws + E_CH);
    const uint4*  xh4 = (const uint4*)(ws + E_XH);

    // A (codes) register-resident: a[i][ks] = code c0+i*16+lr, k-granule ks*4+lq
    short8 a[4][8];
    #pragma unroll
    for (int i = 0; i < 4; ++i)
        #pragma unroll
        for (int ks = 0; ks < 8; ++ks)
            a[i][ks] = ch8[(size_t)(c0 + i * 16 + lr) * 32 + ks * 4 + lq];

    const int half = L >> 5;     // row parity within a 2-row DMA
    const int g32  = L & 31;     // linear dest granule

    // prologue: DMA panel 0 into buf 0 (wave w stages rows [w*16, w*16+16))
    {
        const uint4* src = xh4 + (size_t)(tok0 + w * 16) * 32;
        #pragma unroll
        for (int q = 0; q < 8; ++q) {
            int rrel = 2 * q + half;
            int sg   = g32 ^ (rrel & 7);              // pre-swizzled source
            gl_lds16(src + (size_t)rrel * 32 + sg,
                     &sTok[0][(w * 16 + 2 * q) * 256]);
        }
    }
    __syncthreads();   // vmcnt(0) drain + barrier: panel 0 resident

    const int mtl = wn * 32 + wm * 16 + lr;   // merge-assigned token-local

    for (int p = 0; p < 32; ++p) {
        const int cur = p & 1;

        // DMA next panel into the dead buffer (lands during compute)
        if (p + 1 < 32) {
            const uint4* src = xh4 + (size_t)(tok0 + (p + 1) * 64 + w * 16) * 32;
            #pragma unroll
            for (int q = 0; q < 8; ++q) {
                int rrel = 2 * q + half;
                int sg   = g32 ^ (rrel & 7);
                gl_lds16(src + (size_t)rrel * 32 + sg,
                         &sTok[cur ^ 1][(w * 16 + 2 * q) * 256]);
            }
        }

        // compute panel p: 8 K=32 steps, A regs x B LDS (wave's 32 tokens)
        f32x4 acc[4][2];
        #pragma unroll
        for (int i = 0; i < 4; ++i)
            #pragma unroll
            for (int j = 0; j < 2; ++j)
                acc[i][j] = (f32x4){0.25f, 0.25f, 0.25f, 0.25f};   // positive-bias

        const ushort* tb = &sTok[cur][0];
        #pragma unroll
        for (int ks = 0; ks < 8; ++ks) {
            short8 b[2];
            #pragma unroll
            for (int j = 0; j < 2; ++j) {
                int row = wn * 32 + j * 16 + lr;
                b[j] = *(const short8*)(tb + row * 256 + (((ks * 4 + lq) ^ (lr & 7)) * 8));
            }
            #pragma unroll
            for (int i = 0; i < 4; ++i)
                #pragma unroll
                for (int j = 0; j < 2; ++j)
                    acc[i][j] = __builtin_amdgcn_mfma_f32_16x16x32_bf16(a[i][ks], b[j], acc[i][j], 0, 0, 0);
        }

        // fold: packed-key top-2 of 16 per (lane, j) + lq butterfly
        #pragma unroll
        for (int j = 0; j < 2; ++j) {
            unsigned h[8], l[8];
            #pragma unroll
            for (int i = 0; i < 4; ++i)
                #pragma unroll
                for (int rp = 0; rp < 2; ++rp) {
                    unsigned e0 = (__float_as_uint(acc[i][j][2 * rp])     & 0xFFFFFF80u) | lw | (i << 4) | (2 * rp);
                    unsigned e1 = (__float_as_uint(acc[i][j][2 * rp + 1]) & 0xFFFFFF80u) | lw | (i << 4) | (2 * rp + 1);
                    h[i * 2 + rp] = umax2(e0, e1);
                    l[i * 2 + rp] = umin2(e0, e1);
                }
            #pragma unroll
            for (int s = 4; s >= 1; s >>= 1)
                #pragma unroll
                for (int q = 0; q < 4; ++q) {
                    if (q < s) {
                        unsigned H = umax2(h[q], h[q + s]);
                        unsigned m = umin2(h[q], h[q + s]);
                        l[q] = umax2(m, umax2(l[q], l[q + s]));
                        h[q] = H;
                    }
                }
            unsigned H = h[0], L2 = l[0];
            #pragma unroll
            for (int off = 16; off <= 32; off <<= 1) {
                unsigned oH = (unsigned)__shfl_xor((int)H, off);
                unsigned oL = (unsigned)__shfl_xor((int)L2, off);
                unsigned m = umin2(H, oH);
                H = umax2(H, oH);
                L2 = umax2(m, umax2(L2, oL));
            }
            if (lq == 0)
                msc[cur][wm][wn * 32 + j * 16 + lr] = make_uint2(H, L2);
        }

        // pipelined pair-merge of panel p-1 (reads msc[cur^1], barrier-protected)
        if (p >= 1 && lq == 0) {
            uint2 A = msc[cur ^ 1][0][mtl];
            uint2 B = msc[cur ^ 1][1][mtl];
            unsigned H = umax2(A.x, B.x);
            unsigned m = umin2(A.x, B.x);
            unsigned L2 = umax2(m, umax2(A.y, B.y));
            int token = tok0 + (p - 1) * 64 + mtl;
            slotb[(size_t)grp * BT + token] = make_uint2(H, L2);
        }

        __syncthreads();   // drains DMA (vmcnt) + orders msc/buffer reuse
    }

    // epilogue: merge panel 31 (buf 1)
    if (lq == 0) {
        uint2 A = msc[1][0][mtl];
        uint2 B = msc[1][1][mtl];
        unsigned H = umax2(A.x, B.x);
        unsigned m = umin2(A.x, B.x);
        unsigned L2 = umax2(m, umax2(A.y, B.y));
        int token = tok0 + 31 * 64 + mtl;
        slotb[(size_t)grp * BT + token] = make_uint2(H, L2);
    }
}

// k_gather (R10-verified): fused candidate-collect + exact np-f32 re-check +
// gather + loss. One wave per token; slot L (= grp L) as raw uint2 packed keys.
__global__ __launch_bounds__(256) void k_gather(const float* __restrict__ x,
                                                const float* __restrict__ cb,
                                                const uint2* __restrict__ slotb,
                                                float* __restrict__ out,
                                                float* __restrict__ lp) {
    __shared__ float4 xls[4][64];
    __shared__ int candk[4][16];
    __shared__ float bsum[4];

    const int w = threadIdx.x >> 6;
    const int L = threadIdx.x & 63;
    const int t = blockIdx.x * 4 + w;

    const float4 xv = ((const float4*)x)[(size_t)t * 64 + L];
    xls[w][L] = xv;

    const uint2 s = slotb[(size_t)L * BT + t];
    float v1 = __uint_as_float(s.x & 0xFFFFFF80u);   // biased (+0.25), monotone
    float v2 = __uint_as_float(s.y & 0xFFFFFF80u);
    int   k1 = L * 128 + (int)(s.x & 127u);
    int   k2 = L * 128 + (int)(s.y & 127u);

    // global argmax (min-k tie)
    float lm = v1; int lk = k1;
    #pragma unroll
    for (int off = 32; off; off >>= 1) {
        float ov = __shfl_xor(lm, off);
        int   ok = __shfl_xor(lk, off);
        if (ov > lm || (ov == lm && ok < lk)) { lm = ov; lk = ok; }
    }
    const float thr = lm - MARGIN;

    int* ct = candk[w];
    if (L == 0) ct[0] = lk;          // argmax always candidate 0
    int ncand = 1;
    #pragma unroll
    for (int ph = 0; ph < 2; ++ph) {
        float vv = ph ? v2 : v1;
        int   kf = ph ? k2 : k1;
        unsigned long long bal = __ballot(vv >= thr);
        while (bal) {
            int src = __ffsll(bal) - 1;
            bal &= bal - 1;
            int kv = __shfl(kf, src);
            if (L == 0 && ncand < 16) ct[ncand] = kv;
            ncand++;
        }
    }
    if (ncand > 16) ncand = 16;

    int best;
    if (ncand <= 1) {
        best = lk;
    } else {
        // x2 (any f32 within ~1e-4 of numpy's: uniform grid shift)
        double dl = (double)xv.x * xv.x + (double)xv.y * xv.y
                  + (double)xv.z * xv.z + (double)xv.w * xv.w;
        #pragma unroll
        for (int off = 32; off; off >>= 1) dl += __shfl_xor(dl, off);
        const float x2 = (float)dl;

        const int g = L >> 2, l4 = L & 3;
        float sex = FLT_MAX;
        int   kk  = 0x7fffffff;
        if (g < ncand) {
            kk = ct[g];
            const float* xr = (const float*)&xls[w][0];
            const float* cr = cb + (size_t)kk * DM;
            float acc = 0.f;
            {
#pragma clang fp contract(off)
                #pragma unroll 8
                for (int m = 0; m < 64; m++) {
                    float p2 = xr[4 * m + l4] * cr[4 * m + l4];
                    acc = acc + p2;
                }
            }
            float t1 = acc + __shfl_xor(acc, 1);   // fl(s0+s1)/fl(s2+s3)
            float xc = t1 + __shfl_xor(t1, 2);     // np 4-acc SSE combine
            sex = x2 - 2.0f * xc;
        }
        #pragma unroll
        for (int off = 32; off; off >>= 1) {
            float os = __shfl_xor(sex, off);
            int   ok = __shfl_xor(kk, off);
            if (os < sex || (os == sex && ok < kk)) { sex = os; kk = ok; }
        }
        best = kk;
    }

    const float4 cv = ((const float4*)cb)[(size_t)best * 64 + L];
    float4 e, q;
    e.x = cv.x - xv.x; q.x = xv.x + e.x;
    e.y = cv.y - xv.y; q.y = xv.y + e.y;
    e.z = cv.z - xv.z; q.z = xv.z + e.z;
    e.w = cv.w - xv.w; q.w = xv.w + e.w;
    ((float4*)out)[(size_t)t * 64 + L] = q;
    if (L == 0) out[QOFF + t] = (float)best;

    float ls = e.x * e.x + e.y * e.y + e.z * e.z + e.w * e.w;
    #pragma unroll
    for (int off = 32; off; off >>= 1) ls += __shfl_xor(ls, off);
    if (L == 0) bsum[w] = ls;
    __syncthreads();
    if (threadIdx.x == 0)
        lp[blockIdx.x] = bsum[0] + bsum[1] + bsum[2] + bsum[3];
}

// ======================= fallback f32 path (round-2, verified) =======================

#define TM    64
#define TK    64
#define NSPLIT 2
#define KPS   (KC / NSPLIT)
#define LDSW  68

__global__ __launch_bounds__(256, 2) void k_main_f32(const float* __restrict__ x,
                                                     const float* __restrict__ cb,
                                                     float* __restrict__ out) {
    __shared__ float xs[TM * LDSW];
    __shared__ float cs[TK * LDSW];

    const int tid = threadIdx.x;
    const int ty = tid >> 4, tx = tid & 15;
    const int split = blockIdx.x & 1;
    const int tb    = blockIdx.x >> 1;
    const int t0    = tb * TM;
    const int kb0   = split * KPS;
    const int txc   = tx & 7;
    const int srow = tid >> 4;
    const int sc4  = tid & 15;
    const float4* x4  = (const float4*)x;
    const float4* cb4 = (const float4*)cb;

    float mv[4][4];
    int   mi[4][4];
    #pragma unroll
    for (int i = 0; i < 4; i++)
        #pragma unroll
        for (int j = 0; j < 4; j++) { mv[i][j] = -FLT_MAX; mi[i][j] = 0; }

    for (int k0 = 0; k0 < KPS; k0 += TK) {
        float dot[4][4];
        #pragma unroll
        for (int i = 0; i < 4; i++)
            #pragma unroll
            for (int j = 0; j < 4; j++) dot[i][j] = 0.f;

        for (int d0 = 0; d0 < DM; d0 += 64) {
            __syncthreads();
            const int d04 = d0 >> 2;
            #pragma unroll
            for (int r = 0; r < 4; r++) {
                int row = srow + 16 * r;
                float4 xv = x4[(size_t)(t0 + row) * 64 + d04 + sc4];
                *(float4*)&xs[row * LDSW + sc4 * 4] = xv;
                int gc = sc4 ^ ((row >> 2) & 7);
                float4 cv = cb4[(size_t)(kb0 + k0 + row) * 64 + d04 + gc];
                *(float4*)&cs[row * LDSW + sc4 * 4] = cv;
            }
            __syncthreads();

            #pragma unroll
            for (int u = 0; u < 16; u++) {
                float4 xa[4];
                #pragma unroll
                for (int i = 0; i < 4; i++)
                    xa[i] = *(const float4*)&xs[(ty * 4 + i) * LDSW + u * 4];
                const int ww = u ^ txc;
                float4 cv[4];
                #pragma unroll
                for (int j = 0; j < 4; j++)
                    cv[j] = *(const float4*)&cs[(tx * 4 + j) * LDSW + ww * 4];
                #pragma unroll
                for (int i = 0; i < 4; i++)
                    #pragma unroll
                    for (int j = 0; j < 4; j++) {
                        dot[i][j] = fmaf(xa[i].x, cv[j].x, dot[i][j]);
                        dot[i][j] = fmaf(xa[i].y, cv[j].y, dot[i][j]);
                        dot[i][j] = fmaf(xa[i].z, cv[j].z, dot[i][j]);
                        dot[i][j] = fmaf(xa[i].w, cv[j].w, dot[i][j]);
                    }
            }
        }

        const int kk0 = kb0 + k0 + tx * 4;
        #pragma unroll
        for (int i = 0; i < 4; i++)
            #pragma unroll
            for (int j = 0; j < 4; j++) {
                float d = dot[i][j];
                int   kk = kk0 + j;
                if (d > mv[i][3]) {
                    if (d > mv[i][1]) {
                        if (d > mv[i][0]) {
                            mv[i][3]=mv[i][2]; mi[i][3]=mi[i][2];
                            mv[i][2]=mv[i][1]; mi[i][2]=mi[i][1];
                            mv[i][1]=mv[i][0]; mi[i][1]=mi[i][0];
                            mv[i][0]=d;        mi[i][0]=kk;
                        } else {
                            mv[i][3]=mv[i][2]; mi[i][3]=mi[i][2];
                            mv[i][2]=mv[i][1]; mi[i][2]=mi[i][1];
                            mv[i][1]=d;        mi[i][1]=kk;
                        }
                    } else {
                        if (d > mv[i][2]) {
                            mv[i][3]=mv[i][2]; mi[i][3]=mi[i][2];
                            mv[i][2]=d;        mi[i][2]=kk;
                        } else {
                            mv[i][3]=d;        mi[i][3]=kk;
                        }
                    }
                }
            }
    }

    #pragma unroll
    for (int i = 0; i < 4; i++) {
        int t = t0 + ty * 4 + i;
        float4 v4 = { mv[i][0], mv[i][1], mv[i][2], mv[i][3] };
        float4 k4 = { (float)mi[i][0], (float)mi[i][1], (float)mi[i][2], (float)mi[i][3] };
        float4* dst = (float4*)(out + (size_t)t * DM + (split * 16 + tx) * 8);
        dst[0] = v4;
        dst[1] = k4;
    }
}

__global__ __launch_bounds__(256) void k_gather_f32(const float* __restrict__ x,
                                                    const float* __restrict__ cb,
                                                    float* __restrict__ out,
                                                    float* __restrict__ lp) {
    __shared__ float4 xls[4][64];
    __shared__ int candk[4][20];
    __shared__ float bsum[4];

    const int w = threadIdx.x >> 6;
    const int L = threadIdx.x & 63;
    const int t = blockIdx.x * 4 + w;

    const float4 xv = ((const float4*)x)[(size_t)t * 64 + L];
    xls[w][L] = xv;
    const float4 f = ((const float4*)(out + (size_t)t * DM))[L];
    const bool even = ((L & 1) == 0);

    double dl = (double)xv.x * xv.x + (double)xv.y * xv.y
              + (double)xv.z * xv.z + (double)xv.w * xv.w;
    #pragma unroll
    for (int off = 32; off; off >>= 1) dl += __shfl_xor(dl, off);
    const float x2 = (float)dl;

    float lm = even ? fmaxf(fmaxf(f.x, f.y), fmaxf(f.z, f.w)) : -FLT_MAX;
    #pragma unroll
    for (int off = 32; off; off >>= 1) lm = fmaxf(lm, __shfl_xor(lm, off));
    const float thr = lm - 5e-5f;

    int ncand = 0;
    #pragma unroll
    for (int j = 0; j < 4; j++) {
        float vj = (j == 0) ? f.x : (j == 1) ? f.y : (j == 2) ? f.z : f.w;
        bool flag = even && (vj >= thr);
        unsigned long long bal = __ballot(flag);
        while (bal) {
            int src = __ffsll(bal) - 1;
            bal &= bal - 1;
            float kv = __shfl(vj, src + 1);
            if (L == 0 && ncand < 20) candk[w][ncand] = (int)kv;
            ncand++;
        }
    }
    if (ncand > 16) ncand = 16;

    int best;
    if (ncand == 1) {
        best = candk[w][0];
    } else {
        const int g = L >> 2, l4 = L & 3;
        float sex = FLT_MAX;
        int   kk  = 0x7fffffff;
        if (g < ncand) {
            kk = candk[w][g];
            const float* xr = (const float*)&xls[w][0];
            const float* cr = cb + (size_t)kk * DM;
            float acc = 0.f;
            {
#pragma clang fp contract(off)
                #pragma unroll 8
                for (int m = 0; m < 64; m++) {
                    float p = xr[4 * m + l4] * cr[4 * m + l4];
                    acc = acc + p;
                }
            }
            float t1 = acc + __shfl_xor(acc, 1);
            float xc = t1 + __shfl_xor(t1, 2);
            sex = x2 - 2.0f * xc;
        }
        #pragma unroll
        for (int off = 32; off; off >>= 1) {
            float os = __shfl_xor(sex, off);
            int   ok = __shfl_xor(kk, off);
            if (os < sex || (os == sex && ok < kk)) { sex = os; kk = ok; }
        }
        best = kk;
    }

    const float4 cv = ((const float4*)cb)[(size_t)best * 64 + L];
    float4 e, q;
    e.x = cv.x - xv.x; q.x = xv.x + e.x;
    e.y = cv.y - xv.y; q.y = xv.y + e.y;
    e.z = cv.z - xv.z; q.z = xv.z + e.z;
    e.w = cv.w - xv.w; q.w = xv.w + e.w;
    ((float4*)out)[(size_t)t * 64 + L] = q;
    if (L == 0) out[QOFF + t] = (float)best;

    float ls = e.x * e.x + e.y * e.y + e.z * e.z + e.w * e.w;
    #pragma unroll
    for (int off = 32; off; off >>= 1) ls += __shfl_xor(ls, off);
    if (L == 0) bsum[w] = ls;
    __syncthreads();
    if (threadIdx.x == 0)
        lp[blockIdx.x] = bsum[0] + bsum[1] + bsum[2] + bsum[3];
}

// ---------------- shared loss finalize ----------------
__global__ __launch_bounds__(256) void k_loss(const float* __restrict__ lp,
                                              float* __restrict__ out) {
    __shared__ double sd[256];
    double s = 0.0;
    for (int i = threadIdx.x; i < BT / 4; i += 256) s += (double)lp[i];
    sd[threadIdx.x] = s;
    __syncthreads();
    for (int st = 128; st; st >>= 1) {
        if (threadIdx.x < st) sd[threadIdx.x] += sd[threadIdx.x + st];
        __syncthreads();
    }
    if (threadIdx.x == 0)
        out[LOFF] = (float)(2.0 * sd[0] / (double)QOFF);
}

extern "C" void kernel_launch(void* const* d_in, const int* in_sizes, int n_in,
                              void* d_out, int out_size, void* d_ws, size_t ws_size,
                              hipStream_t stream) {
    const float* x  = (const float*)d_in[0];
    const float* cb = (const float*)d_in[1];
    float* out = (float*)d_out;

    if (ws_size >= (size_t)WS_NEED) {
        ushort* wsu   = (ushort*)d_ws;
        uint2*  slotb = (uint2*)((char*)d_ws + WS_SLOT_OFF);
        float*  lp    = (float*)((char*)d_ws + WS_LP_OFF);
        k_cvt      <<<6144, 256, 0, stream>>>(x, cb, wsu);
        k_main_mfma<<<512,  256, 0, stream>>>(wsu, slotb);
        k_gather   <<<BT / 4, 256, 0, stream>>>(x, cb, slotb, out, lp);
        k_loss     <<<1,    256, 0, stream>>>(lp, out);
    } else {
        float* lp = (float*)d_ws;
        k_main_f32  <<<(BT / TM) * NSPLIT, 256, 0, stream>>>(x, cb, out);
        k_gather_f32<<<BT / 4,             256, 0, stream>>>(x, cb, out, lp);
        k_loss      <<<1,                  256, 0, stream>>>(lp, out);
    }
}

// Round 13
// 106.453 us; speedup vs baseline: 1.4401x; 1.0087x over previous
//
#include <hip/hip_runtime.h>
#include <float.h>

typedef __attribute__((ext_vector_type(8))) short short8;
typedef __attribute__((ext_vector_type(4))) float f32x4;

#define BT    16384      // B*T tokens
#define DM    256        // embedding dim
#define KC    8192       // codebook size
#define QOFF  (BT * DM)  // start of indices in d_out
#define LOFF  (QOFF + BT)
#define MARGIN 2e-4f

// ws layout (bytes)
#define E_XH 0
#define E_CH (BT * DM)                                   // ushort elems
#define WS_BF16_BYTES ((size_t)(BT * DM + KC * DM) * 2)  // 12582912
#define WS_SLOT_OFF   WS_BF16_BYTES                      // uint2[64][BT] = 8 MB
#define WS_SLOT_BYTES ((size_t)64 * BT * 8)
#define WS_LP_OFF     (WS_SLOT_OFF + WS_SLOT_BYTES)
#define WS_NEED       (WS_LP_OFF + 4096 * 4)

// ======================= MFMA path =======================

__device__ inline ushort bf16rne(float f) {
    unsigned u = __float_as_uint(f);
    return (ushort)((u + 0x7FFFu + ((u >> 16) & 1u)) >> 16);
}
__device__ inline unsigned umax2(unsigned a, unsigned b) { return a > b ? a : b; }
__device__ inline unsigned umin2(unsigned a, unsigned b) { return a < b ? a : b; }

// async global->LDS, 16B per lane; dest = lds base (wave-uniform) + lane*16
__device__ __forceinline__ void gl_lds16(const void* g, void* l) {
    __builtin_amdgcn_global_load_lds(
        (const __attribute__((address_space(1))) void*)g,
        (__attribute__((address_space(3))) void*)l, 16, 0, 0);
}

// k_cvt: one-time bf16 round of x and codebook into ws
__global__ __launch_bounds__(256) void k_cvt(const float* __restrict__ x,
                                             const float* __restrict__ cb,
                                             ushort* __restrict__ ws) {
    const int XN = BT * DM / 4;
    const int CN = KC * DM / 4;
    int idx = blockIdx.x * 256 + threadIdx.x;
    const float4* src;
    ushort* dh; int o;
    if (idx < XN) { src = (const float4*)x; dh = ws + E_XH; o = idx; }
    else {
        o = idx - XN;
        if (o >= CN) return;
        src = (const float4*)cb; dh = ws + E_CH;
    }
    float4 v = src[o];
    ushort4 h;
    h.x = bf16rne(v.x);
    h.y = bf16rne(v.y);
    h.z = bf16rne(v.z);
    h.w = bf16rne(v.w);
    ((ushort4*)dh)[o] = h;
}

// k_main_mfma (R12-verified structure) + explicit 1-deep register
// double-buffer of the B fragments: ks+1's two ds_read_b128 are issued
// BEFORE ks's 8 MFMAs, hiding the ~120cyc LDS latency under the MFMA burst.
// Everything else identical to R12 (code-stationary, 4 waves, 2 blocks/CU,
// a[4][8] reg/AGPR-resident, gload_lds pre-swizzled token staging,
// packed-key top-2 fold, pipelined pair-merge, raw uint2 slots).
__global__ __launch_bounds__(256, 2) void k_main_mfma(const ushort* __restrict__ ws,
                                                      uint2* __restrict__ slotb) {
    __shared__ ushort sTok[2][64 * 256];   // 2 x 32 KB token panels
    __shared__ uint2  msc[2][2][64];       // [buf][wm][token-local], 2 KB

    const int tid = threadIdx.x;
    const int w = tid >> 6, L = tid & 63;
    const int lq = L >> 4, lr = L & 15;
    const int wm = w >> 1, wn = w & 1;
    const int grp   = blockIdx.x >> 3;
    const int chunk = blockIdx.x & 7;
    const int c0    = grp * 128 + wm * 64;
    const int tok0  = chunk * 2048;
    const unsigned lw = ((unsigned)wm << 6) | ((unsigned)lq << 2);

    const short8* ch8 = (const short8*)(ws + E_CH);
    const uint4*  xh4 = (const uint4*)(ws + E_XH);

    // A (codes) register-resident: a[i][ks] = code c0+i*16+lr, k-granule ks*4+lq
    short8 a[4][8];
    #pragma unroll
    for (int i = 0; i < 4; ++i)
        #pragma unroll
        for (int ks = 0; ks < 8; ++ks)
            a[i][ks] = ch8[(size_t)(c0 + i * 16 + lr) * 32 + ks * 4 + lq];

    const int half = L >> 5;     // row parity within a 2-row DMA
    const int g32  = L & 31;     // linear dest granule

    // prologue: DMA panel 0 into buf 0 (wave w stages rows [w*16, w*16+16))
    {
        const uint4* src = xh4 + (size_t)(tok0 + w * 16) * 32;
        #pragma unroll
        for (int q = 0; q < 8; ++q) {
            int rrel = 2 * q + half;
            int sg   = g32 ^ (rrel & 7);              // pre-swizzled source
            gl_lds16(src + (size_t)rrel * 32 + sg,
                     &sTok[0][(w * 16 + 2 * q) * 256]);
        }
    }
    __syncthreads();   // vmcnt(0) drain + barrier: panel 0 resident

    const int mtl = wn * 32 + wm * 16 + lr;   // merge-assigned token-local
    const int sw  = lr & 7;                   // read-side swizzle

    for (int p = 0; p < 32; ++p) {
        const int cur = p & 1;

        // DMA next panel into the dead buffer (lands during compute)
        if (p + 1 < 32) {
            const uint4* src = xh4 + (size_t)(tok0 + (p + 1) * 64 + w * 16) * 32;
            #pragma unroll
            for (int q = 0; q < 8; ++q) {
                int rrel = 2 * q + half;
                int sg   = g32 ^ (rrel & 7);
                gl_lds16(src + (size_t)rrel * 32 + sg,
                         &sTok[cur ^ 1][(w * 16 + 2 * q) * 256]);
            }
        }

        // compute panel p: 8 K=32 steps, A regs x B LDS, B reg-dbuffered
        f32x4 acc[4][2];
        #pragma unroll
        for (int i = 0; i < 4; ++i)
            #pragma unroll
            for (int j = 0; j < 2; ++j)
                acc[i][j] = (f32x4){0.25f, 0.25f, 0.25f, 0.25f};   // positive-bias

        const ushort* tb  = &sTok[cur][0];
        const ushort* rp0 = tb + (wn * 32 + lr) * 256;        // j=0 row base
        const ushort* rp1 = tb + (wn * 32 + 16 + lr) * 256;   // j=1 row base

        short8 bc0, bc1, bn0, bn1;
        {
            int g = ((lq) ^ sw) * 8;                          // ks=0 granule
            bc0 = *(const short8*)(rp0 + g);
            bc1 = *(const short8*)(rp1 + g);
        }
        #pragma unroll
        for (int ks = 0; ks < 8; ++ks) {
            if (ks < 7) {                                     // prefetch ks+1
                int g = (((ks + 1) * 4 + lq) ^ sw) * 8;
                bn0 = *(const short8*)(rp0 + g);
                bn1 = *(const short8*)(rp1 + g);
            }
            #pragma unroll
            for (int i = 0; i < 4; ++i) {
                acc[i][0] = __builtin_amdgcn_mfma_f32_16x16x32_bf16(a[i][ks], bc0, acc[i][0], 0, 0, 0);
                acc[i][1] = __builtin_amdgcn_mfma_f32_16x16x32_bf16(a[i][ks], bc1, acc[i][1], 0, 0, 0);
            }
            bc0 = bn0; bc1 = bn1;
        }

        // fold: packed-key top-2 of 16 per (lane, j) + lq butterfly
        #pragma unroll
        for (int j = 0; j < 2; ++j) {
            unsigned h[8], l[8];
            #pragma unroll
            for (int i = 0; i < 4; ++i)
                #pragma unroll
                for (int rp = 0; rp < 2; ++rp) {
                    unsigned e0 = (__float_as_uint(acc[i][j][2 * rp])     & 0xFFFFFF80u) | lw | (i << 4) | (2 * rp);
                    unsigned e1 = (__float_as_uint(acc[i][j][2 * rp + 1]) & 0xFFFFFF80u) | lw | (i << 4) | (2 * rp + 1);
                    h[i * 2 + rp] = umax2(e0, e1);
                    l[i * 2 + rp] = umin2(e0, e1);
                }
            #pragma unroll
            for (int s = 4; s >= 1; s >>= 1)
                #pragma unroll
                for (int q = 0; q < 4; ++q) {
                    if (q < s) {
                        unsigned H = umax2(h[q], h[q + s]);
                        unsigned m = umin2(h[q], h[q + s]);
                        l[q] = umax2(m, umax2(l[q], l[q + s]));
                        h[q] = H;
                    }
                }
            unsigned H = h[0], L2 = l[0];
            #pragma unroll
            for (int off = 16; off <= 32; off <<= 1) {
                unsigned oH = (unsigned)__shfl_xor((int)H, off);
                unsigned oL = (unsigned)__shfl_xor((int)L2, off);
                unsigned m = umin2(H, oH);
                H = umax2(H, oH);
                L2 = umax2(m, umax2(L2, oL));
            }
            if (lq == 0)
                msc[cur][wm][wn * 32 + j * 16 + lr] = make_uint2(H, L2);
        }

        // pipelined pair-merge of panel p-1 (reads msc[cur^1], barrier-protected)
        if (p >= 1 && lq == 0) {
            uint2 A = msc[cur ^ 1][0][mtl];
            uint2 B = msc[cur ^ 1][1][mtl];
            unsigned H = umax2(A.x, B.x);
            unsigned m = umin2(A.x, B.x);
            unsigned L2 = umax2(m, umax2(A.y, B.y));
            int token = tok0 + (p - 1) * 64 + mtl;
            slotb[(size_t)grp * BT + token] = make_uint2(H, L2);
        }

        __syncthreads();   // drains DMA (vmcnt) + orders msc/buffer reuse
    }

    // epilogue: merge panel 31 (buf 1)
    if (lq == 0) {
        uint2 A = msc[1][0][mtl];
        uint2 B = msc[1][1][mtl];
        unsigned H = umax2(A.x, B.x);
        unsigned m = umin2(A.x, B.x);
        unsigned L2 = umax2(m, umax2(A.y, B.y));
        int token = tok0 + 31 * 64 + mtl;
        slotb[(size_t)grp * BT + token] = make_uint2(H, L2);
    }
}

// k_gather (R10-verified): fused candidate-collect + exact np-f32 re-check +
// gather + loss. One wave per token; slot L (= grp L) as raw uint2 packed keys.
__global__ __launch_bounds__(256) void k_gather(const float* __restrict__ x,
                                                const float* __restrict__ cb,
                                                const uint2* __restrict__ slotb,
                                                float* __restrict__ out,
                                                float* __restrict__ lp) {
    __shared__ float4 xls[4][64];
    __shared__ int candk[4][16];
    __shared__ float bsum[4];

    const int w = threadIdx.x >> 6;
    const int L = threadIdx.x & 63;
    const int t = blockIdx.x * 4 + w;

    const float4 xv = ((const float4*)x)[(size_t)t * 64 + L];
    xls[w][L] = xv;

    const uint2 s = slotb[(size_t)L * BT + t];
    float v1 = __uint_as_float(s.x & 0xFFFFFF80u);   // biased (+0.25), monotone
    float v2 = __uint_as_float(s.y & 0xFFFFFF80u);
    int   k1 = L * 128 + (int)(s.x & 127u);
    int   k2 = L * 128 + (int)(s.y & 127u);

    // global argmax (min-k tie)
    float lm = v1; int lk = k1;
    #pragma unroll
    for (int off = 32; off; off >>= 1) {
        float ov = __shfl_xor(lm, off);
        int   ok = __shfl_xor(lk, off);
        if (ov > lm || (ov == lm && ok < lk)) { lm = ov; lk = ok; }
    }
    const float thr = lm - MARGIN;

    int* ct = candk[w];
    if (L == 0) ct[0] = lk;          // argmax always candidate 0
    int ncand = 1;
    #pragma unroll
    for (int ph = 0; ph < 2; ++ph) {
        float vv = ph ? v2 : v1;
        int   kf = ph ? k2 : k1;
        unsigned long long bal = __ballot(vv >= thr);
        while (bal) {
            int src = __ffsll(bal) - 1;
            bal &= bal - 1;
            int kv = __shfl(kf, src);
            if (L == 0 && ncand < 16) ct[ncand] = kv;
            ncand++;
        }
    }
    if (ncand > 16) ncand = 16;

    int best;
    if (ncand <= 1) {
        best = lk;
    } else {
        // x2 (any f32 within ~1e-4 of numpy's: uniform grid shift)
        double dl = (double)xv.x * xv.x + (double)xv.y * xv.y
                  + (double)xv.z * xv.z + (double)xv.w * xv.w;
        #pragma unroll
        for (int off = 32; off; off >>= 1) dl += __shfl_xor(dl, off);
        const float x2 = (float)dl;

        const int g = L >> 2, l4 = L & 3;
        float sex = FLT_MAX;
        int   kk  = 0x7fffffff;
        if (g < ncand) {
            kk = ct[g];
            const float* xr = (const float*)&xls[w][0];
            const float* cr = cb + (size_t)kk * DM;
            float acc = 0.f;
            {
#pragma clang fp contract(off)
                #pragma unroll 8
                for (int m = 0; m < 64; m++) {
                    float p2 = xr[4 * m + l4] * cr[4 * m + l4];
                    acc = acc + p2;
                }
            }
            float t1 = acc + __shfl_xor(acc, 1);   // fl(s0+s1)/fl(s2+s3)
            float xc = t1 + __shfl_xor(t1, 2);     // np 4-acc SSE combine
            sex = x2 - 2.0f * xc;
        }
        #pragma unroll
        for (int off = 32; off; off >>= 1) {
            float os = __shfl_xor(sex, off);
            int   ok = __shfl_xor(kk, off);
            if (os < sex || (os == sex && ok < kk)) { sex = os; kk = ok; }
        }
        best = kk;
    }

    const float4 cv = ((const float4*)cb)[(size_t)best * 64 + L];
    float4 e, q;
    e.x = cv.x - xv.x; q.x = xv.x + e.x;
    e.y = cv.y - xv.y; q.y = xv.y + e.y;
    e.z = cv.z - xv.z; q.z = xv.z + e.z;
    e.w = cv.w - xv.w; q.w = xv.w + e.w;
    ((float4*)out)[(size_t)t * 64 + L] = q;
    if (L == 0) out[QOFF + t] = (float)best;

    float ls = e.x * e.x + e.y * e.y + e.z * e.z + e.w * e.w;
    #pragma unroll
    for (int off = 32; off; off >>= 1) ls += __shfl_xor(ls, off);
    if (L == 0) bsum[w] = ls;
    __syncthreads();
    if (threadIdx.x == 0)
        lp[blockIdx.x] = bsum[0] + bsum[1] + bsum[2] + bsum[3];
}

// ======================= fallback f32 path (round-2, verified) =======================

#define TM    64
#define TK    64
#define NSPLIT 2
#define KPS   (KC / NSPLIT)
#define LDSW  68

__global__ __launch_bounds__(256, 2) void k_main_f32(const float* __restrict__ x,
                                                     const float* __restrict__ cb,
                                                     float* __restrict__ out) {
    __shared__ float xs[TM * LDSW];
    __shared__ float cs[TK * LDSW];

    const int tid = threadIdx.x;
    const int ty = tid >> 4, tx = tid & 15;
    const int split = blockIdx.x & 1;
    const int tb    = blockIdx.x >> 1;
    const int t0    = tb * TM;
    const int kb0   = split * KPS;
    const int txc   = tx & 7;
    const int srow = tid >> 4;
    const int sc4  = tid & 15;
    const float4* x4  = (const float4*)x;
    const float4* cb4 = (const float4*)cb;

    float mv[4][4];
    int   mi[4][4];
    #pragma unroll
    for (int i = 0; i < 4; i++)
        #pragma unroll
        for (int j = 0; j < 4; j++) { mv[i][j] = -FLT_MAX; mi[i][j] = 0; }

    for (int k0 = 0; k0 < KPS; k0 += TK) {
        float dot[4][4];
        #pragma unroll
        for (int i = 0; i < 4; i++)
            #pragma unroll
            for (int j = 0; j < 4; j++) dot[i][j] = 0.f;

        for (int d0 = 0; d0 < DM; d0 += 64) {
            __syncthreads();
            const int d04 = d0 >> 2;
            #pragma unroll
            for (int r = 0; r < 4; r++) {
                int row = srow + 16 * r;
                float4 xv = x4[(size_t)(t0 + row) * 64 + d04 + sc4];
                *(float4*)&xs[row * LDSW + sc4 * 4] = xv;
                int gc = sc4 ^ ((row >> 2) & 7);
                float4 cv = cb4[(size_t)(kb0 + k0 + row) * 64 + d04 + gc];
                *(float4*)&cs[row * LDSW + sc4 * 4] = cv;
            }
            __syncthreads();

            #pragma unroll
            for (int u = 0; u < 16; u++) {
                float4 xa[4];
                #pragma unroll
                for (int i = 0; i < 4; i++)
                    xa[i] = *(const float4*)&xs[(ty * 4 + i) * LDSW + u * 4];
                const int ww = u ^ txc;
                float4 cv[4];
                #pragma unroll
                for (int j = 0; j < 4; j++)
                    cv[j] = *(const float4*)&cs[(tx * 4 + j) * LDSW + ww * 4];
                #pragma unroll
                for (int i = 0; i < 4; i++)
                    #pragma unroll
                    for (int j = 0; j < 4; j++) {
                        dot[i][j] = fmaf(xa[i].x, cv[j].x, dot[i][j]);
                        dot[i][j] = fmaf(xa[i].y, cv[j].y, dot[i][j]);
                        dot[i][j] = fmaf(xa[i].z, cv[j].z, dot[i][j]);
                        dot[i][j] = fmaf(xa[i].w, cv[j].w, dot[i][j]);
                    }
            }
        }

        const int kk0 = kb0 + k0 + tx * 4;
        #pragma unroll
        for (int i = 0; i < 4; i++)
            #pragma unroll
            for (int j = 0; j < 4; j++) {
                float d = dot[i][j];
                int   kk = kk0 + j;
                if (d > mv[i][3]) {
                    if (d > mv[i][1]) {
                        if (d > mv[i][0]) {
                            mv[i][3]=mv[i][2]; mi[i][3]=mi[i][2];
                            mv[i][2]=mv[i][1]; mi[i][2]=mi[i][1];
                            mv[i][1]=mv[i][0]; mi[i][1]=mi[i][0];
                            mv[i][0]=d;        mi[i][0]=kk;
                        } else {
                            mv[i][3]=mv[i][2]; mi[i][3]=mi[i][2];
                            mv[i][2]=mv[i][1]; mi[i][2]=mi[i][1];
                            mv[i][1]=d;        mi[i][1]=kk;
                        }
                    } else {
                        if (d > mv[i][2]) {
                            mv[i][3]=mv[i][2]; mi[i][3]=mi[i][2];
                            mv[i][2]=d;        mi[i][2]=kk;
                        } else {
                            mv[i][3]=d;        mi[i][3]=kk;
                        }
                    }
                }
            }
    }

    #pragma unroll
    for (int i = 0; i < 4; i++) {
        int t = t0 + ty * 4 + i;
        float4 v4 = { mv[i][0], mv[i][1], mv[i][2], mv[i][3] };
        float4 k4 = { (float)mi[i][0], (float)mi[i][1], (float)mi[i][2], (float)mi[i][3] };
        float4* dst = (float4*)(out + (size_t)t * DM + (split * 16 + tx) * 8);
        dst[0] = v4;
        dst[1] = k4;
    }
}

__global__ __launch_bounds__(256) void k_gather_f32(const float* __restrict__ x,
                                                    const float* __restrict__ cb,
                                                    float* __restrict__ out,
                                                    float* __restrict__ lp) {
    __shared__ float4 xls[4][64];
    __shared__ int candk[4][20];
    __shared__ float bsum[4];

    const int w = threadIdx.x >> 6;
    const int L = threadIdx.x & 63;
    const int t = blockIdx.x * 4 + w;

    const float4 xv = ((const float4*)x)[(size_t)t * 64 + L];
    xls[w][L] = xv;
    const float4 f = ((const float4*)(out + (size_t)t * DM))[L];
    const bool even = ((L & 1) == 0);

    double dl = (double)xv.x * xv.x + (double)xv.y * xv.y
              + (double)xv.z * xv.z + (double)xv.w * xv.w;
    #pragma unroll
    for (int off = 32; off; off >>= 1) dl += __shfl_xor(dl, off);
    const float x2 = (float)dl;

    float lm = even ? fmaxf(fmaxf(f.x, f.y), fmaxf(f.z, f.w)) : -FLT_MAX;
    #pragma unroll
    for (int off = 32; off; off >>= 1) lm = fmaxf(lm, __shfl_xor(lm, off));
    const float thr = lm - 5e-5f;

    int ncand = 0;
    #pragma unroll
    for (int j = 0; j < 4; j++) {
        float vj = (j == 0) ? f.x : (j == 1) ? f.y : (j == 2) ? f.z : f.w;
        bool flag = even && (vj >= thr);
        unsigned long long bal = __ballot(flag);
        while (bal) {
            int src = __ffsll(bal) - 1;
            bal &= bal - 1;
            float kv = __shfl(vj, src + 1);
            if (L == 0 && ncand < 20) candk[w][ncand] = (int)kv;
            ncand++;
        }
    }
    if (ncand > 16) ncand = 16;

    int best;
    if (ncand == 1) {
        best = candk[w][0];
    } else {
        const int g = L >> 2, l4 = L & 3;
        float sex = FLT_MAX;
        int   kk  = 0x7fffffff;
        if (g < ncand) {
            kk = candk[w][g];
            const float* xr = (const float*)&xls[w][0];
            const float* cr = cb + (size_t)kk * DM;
            float acc = 0.f;
            {
#pragma clang fp contract(off)
                #pragma unroll 8
                for (int m = 0; m < 64; m++) {
                    float p = xr[4 * m + l4] * cr[4 * m + l4];
                    acc = acc + p;
                }
            }
            float t1 = acc + __shfl_xor(acc, 1);
            float xc = t1 + __shfl_xor(t1, 2);
            sex = x2 - 2.0f * xc;
        }
        #pragma unroll
        for (int off = 32; off; off >>= 1) {
            float os = __shfl_xor(sex, off);
            int   ok = __shfl_xor(kk, off);
            if (os < sex || (os == sex && ok < kk)) { sex = os; kk = ok; }
        }
        best = kk;
    }

    const float4 cv = ((const float4*)cb)[(size_t)best * 64 + L];
    float4 e, q;
    e.x = cv.x - xv.x; q.x = xv.x + e.x;
    e.y = cv.y - xv.y; q.y = xv.y + e.y;
    e.z = cv.z - xv.z; q.z = xv.z + e.z;
    e.w = cv.w - xv.w; q.w = xv.w + e.w;
    ((float4*)out)[(size_t)t * 64 + L] = q;
    if (L == 0) out[QOFF + t] = (float)best;

    float ls = e.x * e.x + e.y * e.y + e.z * e.z + e.w * e.w;
    #pragma unroll
    for (int off = 32; off; off >>= 1) ls += __shfl_xor(ls, off);
    if (L == 0) bsum[w] = ls;
    __syncthreads();
    if (threadIdx.x == 0)
        lp[blockIdx.x] = bsum[0] + bsum[1] + bsum[2] + bsum[3];
}

// ---------------- shared loss finalize ----------------
__global__ __launch_bounds__(256) void k_loss(const float* __restrict__ lp,
                                              float* __restrict__ out) {
    __shared__ double sd[256];
    double s = 0.0;
    for (int i = threadIdx.x; i < BT / 4; i += 256) s += (double)lp[i];
    sd[threadIdx.x] = s;
    __syncthreads();
    for (int st = 128; st; st >>= 1) {
        if (threadIdx.x < st) sd[threadIdx.x] += sd[threadIdx.x + st];
        __syncthreads();
    }
    if (threadIdx.x == 0)
        out[LOFF] = (float)(2.0 * sd[0] / (double)QOFF);
}

extern "C" void kernel_launch(void* const* d_in, const int* in_sizes, int n_in,
                              void* d_out, int out_size, void* d_ws, size_t ws_size,
                              hipStream_t stream) {
    const float* x  = (const float*)d_in[0];
    const float* cb = (const float*)d_in[1];
    float* out = (float*)d_out;

    if (ws_size >= (size_t)WS_NEED) {
        ushort* wsu   = (ushort*)d_ws;
        uint2*  slotb = (uint2*)((char*)d_ws + WS_SLOT_OFF);
        float*  lp    = (float*)((char*)d_ws + WS_LP_OFF);
        k_cvt      <<<6144, 256, 0, stream>>>(x, cb, wsu);
        k_main_mfma<<<512,  256, 0, stream>>>(wsu, slotb);
        k_gather   <<<BT / 4, 256, 0, stream>>>(x, cb, slotb, out, lp);
        k_loss     <<<1,    256, 0, stream>>>(lp, out);
    } else {
        float* lp = (float*)d_ws;
        k_main_f32  <<<(BT / TM) * NSPLIT, 256, 0, stream>>>(x, cb, out);
        k_gather_f32<<<BT / 4,             256, 0, stream>>>(x, cb, out, lp);
        k_loss      <<<1,                  256, 0, stream>>>(lp, out);
    }
}